// Round 2
// baseline (636.294 us; speedup 1.0000x reference)
//
#include <hip/hip_runtime.h>
#include <hip/hip_bf16.h>

// LSTM cell: z = [x|h] @ Wstack^T + b ; gates -> c_t, h_t.
// M=4096 (batch), K=4096 (2048 input + 2048 hidden), N=2048 per gate x 4 gates.
// bf16 MFMA GEMM (m97 structure: 16KB LDS/K-step, global_load_lds w=16).
// Each wave computes a 32x32 (m,h) patch for ALL 4 gates -> epilogue fully local.
// R1: XOR bank-swizzle of 16B chunks within each 32-short LDS row
//     (stored_chunk = chunk ^ ((row>>1)&3)) — kills the 8-way ds_read_b128
//     conflict of the naive row-major layout while keeping the DMA write side
//     lane-contiguous (global source chunk is permuted instead).

#define M_DIM 4096
#define K_DIM 4096
#define H_DIM 2048
#define BM 128
#define BN 32
#define BK 32

typedef __attribute__((ext_vector_type(8))) short bf16x8;
typedef __attribute__((ext_vector_type(4))) float f32x4;

__device__ __forceinline__ unsigned short f2bf(float f) {
    union { float f; unsigned int u; } v; v.f = f;
    unsigned int u = v.u;
    unsigned int r = u + 0x7FFFu + ((u >> 16) & 1u);   // round-to-nearest-even
    return (unsigned short)(r >> 16);
}

__device__ __forceinline__ float sigmoid_f(float x) {
    return 1.0f / (1.0f + __expf(-x));
}
__device__ __forceinline__ float tanh_f(float x) {
    return 2.0f / (1.0f + __expf(-2.0f * x)) - 1.0f;
}

// Swizzled short-offset within a [rows][BK] tile: 16B chunk c at row r is
// stored at chunk (c ^ ((r>>1)&3)). koff in shorts (0..31).
__device__ __forceinline__ int sw_off(int row, int koff) {
    int c  = koff >> 3;
    int sc = c ^ ((row >> 1) & 3);
    return row * BK + sc * 8 + (koff & 7);
}

__device__ __forceinline__ void async_load16(const unsigned short* g, unsigned short* l) {
    __builtin_amdgcn_global_load_lds(
        (const __attribute__((address_space(1))) void*)g,
        (__attribute__((address_space(3))) void*)l,
        16, 0, 0);
}

// ---------------- fp32 -> bf16 conversion prepass (DMA path) ----------------
// xh_bf: [4096][4096] = [x_t | h_t_1]; w_bf: [8192][4096] = stacked Wi,Wf,Wo,Wc
__global__ void convert_all(const float* __restrict__ x, const float* __restrict__ h,
                            const float* __restrict__ Wi, const float* __restrict__ Wf,
                            const float* __restrict__ Wo, const float* __restrict__ Wc,
                            ushort4* __restrict__ xh_bf, ushort4* __restrict__ w_bf) {
    const int XHG = (M_DIM * K_DIM) / 4;          // 4,194,304 float4-groups
    int gid = blockIdx.x * 256 + threadIdx.x;     // 0 .. 12,582,911
    float4 v;
    ushort4* dst;
    if (gid < XHG) {
        int e = gid * 4;
        int row = e >> 12;            // /4096
        int col = e & 4095;
        if (col < 2048) v = *(const float4*)&x[row * 2048 + col];
        else            v = *(const float4*)&h[row * 2048 + (col - 2048)];
        dst = xh_bf + gid;
    } else {
        int g2 = gid - XHG;
        long e = (long)g2 * 4;
        int row = (int)(e >> 12);     // 0..8191
        int col = (int)(e & 4095);
        int gate = row >> 11;
        const float* Ws = (gate == 0) ? Wi : (gate == 1) ? Wf : (gate == 2) ? Wo : Wc;
        v = *(const float4*)&Ws[(long)(row & 2047) * 4096 + col];
        dst = w_bf + g2;
    }
    *dst = make_ushort4(f2bf(v.x), f2bf(v.y), f2bf(v.z), f2bf(v.w));
}

// ---------------- fused LSTM GEMM ----------------
// grid: (H_DIM/BN = 64, M_DIM/BM = 32), block 256.
// Wave w handles m in [32w,32w+32), h in [0,32) of the block tile, all 4 gates.
template <bool DMA>
__global__ __launch_bounds__(256) void lstm_gemm(
    const unsigned short* __restrict__ xh_bf, const unsigned short* __restrict__ w_bf,
    const float* __restrict__ x_t, const float* __restrict__ h_t_1,
    const float* __restrict__ Wi, const float* __restrict__ Wf,
    const float* __restrict__ Wo, const float* __restrict__ Wc,
    const float* __restrict__ b_i, const float* __restrict__ b_f,
    const float* __restrict__ b_o, const float* __restrict__ b_c,
    const float* __restrict__ c_prev,
    float* __restrict__ h_out, float* __restrict__ c_out) {

    __shared__ __align__(16) unsigned short sA[BM * BK];      // [128][32] 8KB
    __shared__ __align__(16) unsigned short sB[4 * BN * BK];  // [4][32][32] 8KB

    const int tid  = threadIdx.x;
    const int w    = tid >> 6;
    const int lane = tid & 63;
    const int l16  = lane & 15;
    const int quad = lane >> 4;

    const int mBase = blockIdx.y * BM;
    const int nBase = blockIdx.x * BN;

    f32x4 acc[4][2][2] = {};   // [gate][mt][nt]

    for (int k0 = 0; k0 < K_DIM; k0 += BK) {
        __syncthreads();   // protect LDS from overwrite while prior reads in flight
        if constexpr (DMA) {
#pragma unroll
            for (int r = 0; r < 2; ++r) {           // A tile: 512 chunks of 16B
                int cc  = r * 256 + tid;
                int row = cc >> 2;
                int lc  = (cc & 3) ^ ((row >> 1) & 3);   // logical chunk for this slot
                async_load16(xh_bf + (size_t)(mBase + row) * K_DIM + k0 + lc * 8,
                             &sA[cc * 8]);
            }
#pragma unroll
            for (int r = 0; r < 2; ++r) {           // B tiles (4 gates)
                int cc   = r * 256 + tid;
                int gate = cc >> 7;
                int row  = (cc >> 2) & 31;
                int lc   = (cc & 3) ^ ((row >> 1) & 3);
                async_load16(w_bf + (size_t)(gate * H_DIM + nBase + row) * K_DIM + k0 + lc * 8,
                             &sB[cc * 8]);
            }
        } else {
            const float* Asrc = (k0 < 2048) ? x_t : h_t_1;
            int kloc = k0 & 2047;
#pragma unroll
            for (int r = 0; r < 4; ++r) {           // A: 1024 float4-chunks (8 shorts... 4 floats)
                int cc  = r * 256 + tid;
                int row = cc >> 3;
                int ko  = (cc & 7) * 4;             // short offset, 0..28
                float4 v = *(const float4*)&Asrc[(size_t)(mBase + row) * 2048 + kloc + ko];
                *(ushort4*)&sA[sw_off(row, ko)] =
                    make_ushort4(f2bf(v.x), f2bf(v.y), f2bf(v.z), f2bf(v.w));
            }
            const float* Wg[4] = {Wi, Wf, Wo, Wc};
#pragma unroll
            for (int g = 0; g < 4; ++g) {           // B: 256 chunks per gate
                int row = tid >> 3;
                int ko  = (tid & 7) * 4;
                float4 v = *(const float4*)&Wg[g][(size_t)(nBase + row) * K_DIM + k0 + ko];
                *(ushort4*)&sB[g * (BN * BK) + sw_off(row, ko)] =
                    make_ushort4(f2bf(v.x), f2bf(v.y), f2bf(v.z), f2bf(v.w));
            }
        }
        __syncthreads();   // drains vmcnt for global_load_lds too

        bf16x8 av[2];
#pragma unroll
        for (int mt = 0; mt < 2; ++mt) {
            int row = w * 32 + mt * 16 + l16;
            av[mt] = *(const bf16x8*)&sA[sw_off(row, quad * 8)];
        }
        bf16x8 bv[4][2];
#pragma unroll
        for (int g = 0; g < 4; ++g)
#pragma unroll
            for (int nt = 0; nt < 2; ++nt) {
                int row = nt * 16 + l16;
                bv[g][nt] = *(const bf16x8*)&sB[g * (BN * BK) + sw_off(row, quad * 8)];
            }

#pragma unroll
        for (int g = 0; g < 4; ++g)
#pragma unroll
            for (int mt = 0; mt < 2; ++mt)
#pragma unroll
                for (int nt = 0; nt < 2; ++nt)
                    acc[g][mt][nt] = __builtin_amdgcn_mfma_f32_16x16x32_bf16(
                        av[mt], bv[g][nt], acc[g][mt][nt], 0, 0, 0);
    }

    // Epilogue: wave-local gates -> c_t, h_t. D layout: col=lane&15, row=quad*4+i.
#pragma unroll
    for (int mt = 0; mt < 2; ++mt) {
#pragma unroll
        for (int nt = 0; nt < 2; ++nt) {
            int hcol = nBase + nt * 16 + l16;
            float bi = b_i[hcol], bf = b_f[hcol], bo = b_o[hcol], bc = b_c[hcol];
#pragma unroll
            for (int i = 0; i < 4; ++i) {
                int m = mBase + w * 32 + mt * 16 + quad * 4 + i;
                float zi = acc[0][mt][nt][i] + bi;
                float zf = acc[1][mt][nt][i] + bf;
                float zo = acc[2][mt][nt][i] + bo;
                float zc = acc[3][mt][nt][i] + bc;
                float ig = sigmoid_f(zi);
                float fg = sigmoid_f(zf);
                float og = sigmoid_f(zo);
                float ch = tanh_f(zc);
                size_t idx = (size_t)m * H_DIM + hcol;
                float c = fg * c_prev[idx] + ig * ch;
                c_out[idx] = c;
                h_out[idx] = og * tanh_f(c);
            }
        }
    }
}

extern "C" void kernel_launch(void* const* d_in, const int* in_sizes, int n_in,
                              void* d_out, int out_size, void* d_ws, size_t ws_size,
                              hipStream_t stream) {
    const float* x_t   = (const float*)d_in[0];
    const float* h_t_1 = (const float*)d_in[1];
    const float* c_t_1 = (const float*)d_in[2];
    const float* W_i   = (const float*)d_in[3];
    const float* b_i   = (const float*)d_in[4];
    const float* W_f   = (const float*)d_in[5];
    const float* b_f   = (const float*)d_in[6];
    const float* W_o   = (const float*)d_in[7];
    const float* b_o   = (const float*)d_in[8];
    const float* W_c   = (const float*)d_in[9];
    const float* b_c   = (const float*)d_in[10];

    float* h_out = (float*)d_out;
    float* c_out = h_out + (size_t)M_DIM * H_DIM;

    dim3 grid(H_DIM / BN, M_DIM / BM);   // (64, 32)

    const size_t need = (size_t)M_DIM * K_DIM * 2 + (size_t)4 * H_DIM * K_DIM * 2; // 96 MB
    if (ws_size >= need) {
        unsigned short* xh_bf = (unsigned short*)d_ws;
        unsigned short* w_bf  = xh_bf + (size_t)M_DIM * K_DIM;
        int total_groups = (M_DIM * K_DIM + 4 * H_DIM * K_DIM) / 4;  // 12,582,912
        convert_all<<<total_groups / 256, 256, 0, stream>>>(
            x_t, h_t_1, W_i, W_f, W_o, W_c, (ushort4*)xh_bf, (ushort4*)w_bf);
        lstm_gemm<true><<<grid, 256, 0, stream>>>(
            xh_bf, w_bf, nullptr, nullptr, nullptr, nullptr, nullptr, nullptr,
            b_i, b_f, b_o, b_c, c_t_1, h_out, c_out);
    } else {
        lstm_gemm<false><<<grid, 256, 0, stream>>>(
            nullptr, nullptr, x_t, h_t_1, W_i, W_f, W_o, W_c,
            b_i, b_f, b_o, b_c, c_t_1, h_out, c_out);
    }
}

// Round 3
// 613.003 us; speedup vs baseline: 1.0380x; 1.0380x over previous
//
#include <hip/hip_runtime.h>
#include <hip/hip_bf16.h>

// LSTM cell: z = [x|h] @ Wstack^T + b ; gates -> c_t, h_t.
// M=4096 (batch), K=4096, N=2048 per gate x 4 gates. bf16 MFMA GEMM.
// R1: XOR bank-swizzle -> SQ_LDS_BANK_CONFLICT measured 0. KEEP.
// R2: BK 32->64 (halve barrier-drain count; 32KB LDS keeps >=3 blk/CU),
//     per-K16-half fragment scoping to hold live VGPRs ~124 (4 waves/SIMD),
//     convert prepass: 16B loads AND 16B stores (was 8B stores).

#define M_DIM 4096
#define K_DIM 4096
#define H_DIM 2048
#define BM 128
#define BN 32
#define BK 64

typedef __attribute__((ext_vector_type(8))) short bf16x8;
typedef __attribute__((ext_vector_type(8))) unsigned short u16x8;
typedef __attribute__((ext_vector_type(4))) float f32x4;

__device__ __forceinline__ unsigned short f2bf(float f) {
    union { float f; unsigned int u; } v; v.f = f;
    unsigned int u = v.u;
    unsigned int r = u + 0x7FFFu + ((u >> 16) & 1u);   // round-to-nearest-even
    return (unsigned short)(r >> 16);
}

__device__ __forceinline__ float sigmoid_f(float x) {
    return 1.0f / (1.0f + __expf(-x));
}
__device__ __forceinline__ float tanh_f(float x) {
    return 2.0f / (1.0f + __expf(-2.0f * x)) - 1.0f;
}

// Swizzled short-offset in a [rows][64] tile. 16B chunk c of row r stored at
// chunk (c ^ (r&7)): row base bank is constant (128B row = 32 banks), the xor
// spreads the 8 chunk slots over all 8 four-bank groups -> 2 lanes/bank (free).
__device__ __forceinline__ int sw64(int row, int koff) {
    int c  = koff >> 3;
    int sc = c ^ (row & 7);
    return row * BK + sc * 8 + (koff & 7);
}

__device__ __forceinline__ void async_load16(const unsigned short* g, unsigned short* l) {
    __builtin_amdgcn_global_load_lds(
        (const __attribute__((address_space(1))) void*)g,
        (__attribute__((address_space(3))) void*)l,
        16, 0, 0);
}

// ---------------- fp32 -> bf16 conversion prepass ----------------
// xh_bf: [4096][4096] = [x_t | h_t_1]; w_bf: [8192][4096] = Wi,Wf,Wo,Wc stacked.
// One thread = 8 elems: two float4 loads, one 16B store. Grid exactly covers.
__global__ __launch_bounds__(256) void convert_all(
        const float* __restrict__ x, const float* __restrict__ h,
        const float* __restrict__ Wi, const float* __restrict__ Wf,
        const float* __restrict__ Wo, const float* __restrict__ Wc,
        u16x8* __restrict__ xh_bf, u16x8* __restrict__ w_bf) {
    const int XHT = (M_DIM * K_DIM) / 8;          // 2,097,152
    int t = blockIdx.x * 256 + threadIdx.x;       // 0 .. 6,291,455
    const float* src;
    u16x8* dst;
    if (t < XHT) {
        int e = t * 8;
        int row = e >> 12;
        int col = e & 4095;
        src = (col < 2048) ? &x[(size_t)row * 2048 + col]
                           : &h[(size_t)row * 2048 + (col - 2048)];
        dst = xh_bf + t;
    } else {
        int g2 = t - XHT;                         // 0 .. 4,194,303
        long e = (long)g2 * 8;
        int row = (int)(e >> 12);                 // 0..8191
        int col = (int)(e & 4095);
        int gate = row >> 11;
        const float* Ws = (gate == 0) ? Wi : (gate == 1) ? Wf : (gate == 2) ? Wo : Wc;
        src = &Ws[(size_t)(row & 2047) * 4096 + col];
        dst = w_bf + g2;
    }
    float4 v0 = *(const float4*)src;
    float4 v1 = *(const float4*)(src + 4);
    u16x8 o;
    o[0] = f2bf(v0.x); o[1] = f2bf(v0.y); o[2] = f2bf(v0.z); o[3] = f2bf(v0.w);
    o[4] = f2bf(v1.x); o[5] = f2bf(v1.y); o[6] = f2bf(v1.z); o[7] = f2bf(v1.w);
    *dst = o;
}

// ---------------- fused LSTM GEMM ----------------
// grid (H/BN=64, M/BM=32), block 256 (4 waves). Wave w: m in [32w,32w+32),
// h-cols [0,32) of the block tile, all 4 gates (epilogue fully wave-local).
template <bool DMA>
__global__ __launch_bounds__(256) void lstm_gemm(
    const unsigned short* __restrict__ xh_bf, const unsigned short* __restrict__ w_bf,
    const float* __restrict__ x_t, const float* __restrict__ h_t_1,
    const float* __restrict__ Wi, const float* __restrict__ Wf,
    const float* __restrict__ Wo, const float* __restrict__ Wc,
    const float* __restrict__ b_i, const float* __restrict__ b_f,
    const float* __restrict__ b_o, const float* __restrict__ b_c,
    const float* __restrict__ c_prev,
    float* __restrict__ h_out, float* __restrict__ c_out) {

    __shared__ __align__(16) unsigned short sA[BM * BK];      // [128][64] 16KB
    __shared__ __align__(16) unsigned short sB[4 * BN * BK];  // [4][32][64] 16KB

    const int tid  = threadIdx.x;
    const int w    = tid >> 6;
    const int lane = tid & 63;
    const int l16  = lane & 15;
    const int quad = lane >> 4;

    const int mBase = blockIdx.y * BM;
    const int nBase = blockIdx.x * BN;

    f32x4 acc[4][2][2] = {};   // [gate][mt][nt]

    for (int k0 = 0; k0 < K_DIM; k0 += BK) {
        __syncthreads();   // protect LDS while prior step's reads retire
        if constexpr (DMA) {
#pragma unroll
            for (int r = 0; r < 4; ++r) {           // A: 1024 chunks of 16B
                int cc   = r * 256 + tid;
                int row  = cc >> 3;
                int lc   = (cc & 7) ^ (row & 7);    // logical chunk for this slot
                async_load16(xh_bf + (size_t)(mBase + row) * K_DIM + k0 + lc * 8,
                             &sA[cc * 8]);
            }
#pragma unroll
            for (int r = 0; r < 4; ++r) {           // B: 4 gates x 32 rows x 8 chunks
                int cc   = r * 256 + tid;
                int gate = cc >> 8;
                int row  = (cc >> 3) & 31;
                int lc   = (cc & 7) ^ (row & 7);
                async_load16(w_bf + (size_t)(gate * H_DIM + nBase + row) * K_DIM + k0 + lc * 8,
                             &sB[cc * 8]);
            }
        } else {
            const float* Asrc = (k0 < 2048) ? x_t : h_t_1;
            int kloc = k0 & 2047;
#pragma unroll
            for (int r = 0; r < 8; ++r) {           // A: 2048 float4 chunks
                int cc  = r * 256 + tid;
                int row = cc >> 4;
                int ko  = (cc & 15) * 4;
                float4 v = *(const float4*)&Asrc[(size_t)(mBase + row) * 2048 + kloc + ko];
                *(ushort4*)&sA[sw64(row, ko)] =
                    make_ushort4(f2bf(v.x), f2bf(v.y), f2bf(v.z), f2bf(v.w));
            }
            const float* Wg[4] = {Wi, Wf, Wo, Wc};
#pragma unroll
            for (int r = 0; r < 8; ++r) {           // B: 2048 float4 chunks
                int cc   = r * 256 + tid;
                int gate = cc >> 9;
                int row  = (cc >> 4) & 31;
                int ko   = (cc & 15) * 4;
                float4 v = *(const float4*)&Wg[gate][(size_t)(nBase + row) * K_DIM + k0 + ko];
                *(ushort4*)&sB[gate * (BN * BK) + sw64(row, ko)] =
                    make_ushort4(f2bf(v.x), f2bf(v.y), f2bf(v.z), f2bf(v.w));
            }
        }
        __syncthreads();   // drains vmcnt for global_load_lds too

        // Two K16 halves; fragments scoped per half to bound live VGPRs.
#pragma unroll
        for (int hk = 0; hk < 2; ++hk) {
            bf16x8 av[2];
#pragma unroll
            for (int mt = 0; mt < 2; ++mt) {
                int row = w * 32 + mt * 16 + l16;
                av[mt] = *(const bf16x8*)&sA[sw64(row, hk * 32 + quad * 8)];
            }
            bf16x8 bv[4][2];
#pragma unroll
            for (int g = 0; g < 4; ++g)
#pragma unroll
                for (int nt = 0; nt < 2; ++nt) {
                    int row = nt * 16 + l16;
                    bv[g][nt] = *(const bf16x8*)&sB[g * (BN * BK) + sw64(row, hk * 32 + quad * 8)];
                }
#pragma unroll
            for (int g = 0; g < 4; ++g)
#pragma unroll
                for (int mt = 0; mt < 2; ++mt)
#pragma unroll
                    for (int nt = 0; nt < 2; ++nt)
                        acc[g][mt][nt] = __builtin_amdgcn_mfma_f32_16x16x32_bf16(
                            av[mt], bv[g][nt], acc[g][mt][nt], 0, 0, 0);
        }
    }

    // Epilogue: wave-local gates -> c_t, h_t. D layout: col=lane&15, row=quad*4+i.
#pragma unroll
    for (int mt = 0; mt < 2; ++mt) {
#pragma unroll
        for (int nt = 0; nt < 2; ++nt) {
            int hcol = nBase + nt * 16 + l16;
            float bi = b_i[hcol], bf = b_f[hcol], bo = b_o[hcol], bc = b_c[hcol];
#pragma unroll
            for (int i = 0; i < 4; ++i) {
                int m = mBase + w * 32 + mt * 16 + quad * 4 + i;
                float zi = acc[0][mt][nt][i] + bi;
                float zf = acc[1][mt][nt][i] + bf;
                float zo = acc[2][mt][nt][i] + bo;
                float zc = acc[3][mt][nt][i] + bc;
                float ig = sigmoid_f(zi);
                float fg = sigmoid_f(zf);
                float og = sigmoid_f(zo);
                float ch = tanh_f(zc);
                size_t idx = (size_t)m * H_DIM + hcol;
                float c = fg * c_prev[idx] + ig * ch;
                c_out[idx] = c;
                h_out[idx] = og * tanh_f(c);
            }
        }
    }
}

extern "C" void kernel_launch(void* const* d_in, const int* in_sizes, int n_in,
                              void* d_out, int out_size, void* d_ws, size_t ws_size,
                              hipStream_t stream) {
    const float* x_t   = (const float*)d_in[0];
    const float* h_t_1 = (const float*)d_in[1];
    const float* c_t_1 = (const float*)d_in[2];
    const float* W_i   = (const float*)d_in[3];
    const float* b_i   = (const float*)d_in[4];
    const float* W_f   = (const float*)d_in[5];
    const float* b_f   = (const float*)d_in[6];
    const float* W_o   = (const float*)d_in[7];
    const float* b_o   = (const float*)d_in[8];
    const float* W_c   = (const float*)d_in[9];
    const float* b_c   = (const float*)d_in[10];

    float* h_out = (float*)d_out;
    float* c_out = h_out + (size_t)M_DIM * H_DIM;

    dim3 grid(H_DIM / BN, M_DIM / BM);   // (64, 32)

    const size_t need = (size_t)M_DIM * K_DIM * 2 + (size_t)4 * H_DIM * K_DIM * 2; // 96 MB
    if (ws_size >= need) {
        unsigned short* xh_bf = (unsigned short*)d_ws;
        unsigned short* w_bf  = xh_bf + (size_t)M_DIM * K_DIM;
        int total_threads = (M_DIM * K_DIM + 4 * H_DIM * K_DIM) / 8;  // 6,291,456
        convert_all<<<total_threads / 256, 256, 0, stream>>>(
            x_t, h_t_1, W_i, W_f, W_o, W_c, (u16x8*)xh_bf, (u16x8*)w_bf);
        lstm_gemm<true><<<grid, 256, 0, stream>>>(
            xh_bf, w_bf, nullptr, nullptr, nullptr, nullptr, nullptr, nullptr,
            b_i, b_f, b_o, b_c, c_t_1, h_out, c_out);
    } else {
        lstm_gemm<false><<<grid, 256, 0, stream>>>(
            nullptr, nullptr, x_t, h_t_1, W_i, W_f, W_o, W_c,
            b_i, b_f, b_o, b_c, c_t_1, h_out, c_out);
    }
}